// Round 6
// baseline (260.653 us; speedup 1.0000x reference)
//
#include <hip/hip_runtime.h>
#include <hip/hip_bf16.h>
#include <hip/hip_cooperative_groups.h>
#include <math.h>

namespace cg = cooperative_groups;

// Problem constants: B=32, L=128, D=512, Qn=16, N=512, P=64
#define DD    512
#define QN    16
#define NTOK  4096
#define MEXT  4112           // NTOK + QN
#define MPAD  4224           // 66 * 64
#define NGRP  512
#define PP    64
#define NB    576            // padded B rows: 512 Wv + 16 score + 48 pad (9 tiles)
#define SCALE 0.04419417382415922f   // 1/sqrt(512)

#define GRID  512            // cooperative grid: 2 blocks/CU co-resident

typedef __bf16 bf16x8 __attribute__((ext_vector_type(8)));
typedef float  f32x4  __attribute__((ext_vector_type(4)));

static __device__ __forceinline__ ushort f2bf(float f) {
    __hip_bfloat16 h = __float2bfloat16(f);
    return *reinterpret_cast<ushort*>(&h);
}
static __device__ __forceinline__ float2 bfp2f2(unsigned int v) {
    float2 r;
    r.x = __uint_as_float(v << 16);
    r.y = __uint_as_float(v & 0xffff0000u);
    return r;
}

// ---------------------------------------------------------------------------
// Fused cooperative kernel: pack -> grid.sync -> GEMM -> grid.sync -> agg
// LDS arena overlaid per phase (grid.sync's block barrier covers aliasing).
// ---------------------------------------------------------------------------
__global__ __launch_bounds__(256) void fused(
    const float* __restrict__ patch, const float* __restrict__ query,
    const float* __restrict__ Wk,    const float* __restrict__ bk,
    const float* __restrict__ Wv,    const float* __restrict__ bv,
    const float* __restrict__ Wf,    const float* __restrict__ bf,
    const int* __restrict__ indices, const void* __restrict__ pmask,
    ushort* __restrict__ Xb, ushort* __restrict__ Bb, float* __restrict__ c0,
    ushort* __restrict__ VpH, float* __restrict__ S, float* __restrict__ out)
{
    __shared__ __align__(16) unsigned char arena[18432];
    cg::grid_group grid = cg::this_grid();
    const int tid = threadIdx.x;

    // ===== Phase 0: pack (1264 work units, block-stride) ====================
    //  [0,1056)    : Xb = bf16([patch ; Q0 ; zeros])          (4224 x 512)
    //  [1056,1120) : Bb rows 0..511 = bf16(Wv^T)  (64x64 LDS transpose)
    //  [1120,1132) : Bb rows 528..575 = 0
    //  [1132,1264) : Bb rows 512..527 = bf16(Wk @ Q0^T), + c0[q] = bk.Q0[q]
    {
        float (*T)[65] = (float(*)[65])arena;            // 16640 B
        for (int b = blockIdx.x; b < 1264; b += GRID) {
            if (b < 1056) {
                const int e0 = b * 2048 + tid * 8;
                const int row = e0 >> 9, c = e0 & 511;
                float v[8];
                if (row < NTOK) {
                    const float4 a0 = *(const float4*)&patch[(size_t)row * DD + c];
                    const float4 a1 = *(const float4*)&patch[(size_t)row * DD + c + 4];
                    v[0]=a0.x; v[1]=a0.y; v[2]=a0.z; v[3]=a0.w;
                    v[4]=a1.x; v[5]=a1.y; v[6]=a1.z; v[7]=a1.w;
                } else if (row < MEXT) {
                    const float4 a0 = *(const float4*)&query[(size_t)(row - NTOK) * DD + c];
                    const float4 a1 = *(const float4*)&query[(size_t)(row - NTOK) * DD + c + 4];
                    v[0]=a0.x; v[1]=a0.y; v[2]=a0.z; v[3]=a0.w;
                    v[4]=a1.x; v[5]=a1.y; v[6]=a1.z; v[7]=a1.w;
                } else {
#pragma unroll
                    for (int j = 0; j < 8; ++j) v[j] = 0.f;
                }
                ushort o[8];
#pragma unroll
                for (int j = 0; j < 8; ++j) o[j] = f2bf(v[j]);
                *(uint4*)&Xb[e0] = *(const uint4*)o;
            } else if (b < 1120) {                // Wv transpose, 64x64 tile
                const int t = b - 1056;
                const int k0 = (t >> 3) * 64, n0 = (t & 7) * 64;
#pragma unroll
                for (int j = 0; j < 16; ++j) {
                    const int idx = tid + j * 256;
                    const int r = idx >> 6, c = idx & 63;
                    T[r][c] = Wv[(size_t)(k0 + r) * DD + n0 + c];
                }
                __syncthreads();
#pragma unroll
                for (int j = 0; j < 16; ++j) {
                    const int idx = tid + j * 256;
                    const int r = idx >> 6, c = idx & 63;
                    Bb[(size_t)(n0 + r) * DD + k0 + c] = f2bf(T[c][r]);
                }
                __syncthreads();                  // T reused next b iteration
            } else if (b < 1132) {                // zero rows 528..575
                const int e0 = (b - 1120) * 2048 + tid * 8;
                *(uint4*)&Bb[(size_t)528 * DD + e0] = make_uint4(0, 0, 0, 0);
            } else {                              // A (score B-rows) + c0
                const int wave = tid >> 6, lane = tid & 63;
                const int g = (b - 1132) * 4 + wave;
                if (g < DD) {
                    const int e = g;
                    float x[8];
#pragma unroll
                    for (int j = 0; j < 8; ++j) x[j] = Wk[e * DD + j * 64 + lane];
                    for (int q = 0; q < QN; ++q) {
                        float s = 0.f;
#pragma unroll
                        for (int j = 0; j < 8; ++j) s += x[j] * query[q * DD + j * 64 + lane];
#pragma unroll
                        for (int off = 32; off > 0; off >>= 1) s += __shfl_down(s, off, 64);
                        if (lane == 0) Bb[(size_t)(DD + q) * DD + e] = f2bf(s);
                    }
                } else {
                    const int q = g - DD;
                    float s = 0.f;
#pragma unroll
                    for (int j = 0; j < 8; ++j)
                        s += bk[j * 64 + lane] * query[q * DD + j * 64 + lane];
#pragma unroll
                    for (int off = 32; off > 0; off >>= 1) s += __shfl_down(s, off, 64);
                    if (lane == 0) c0[q] = s;
                }
            }
        }
    }

    grid.sync();

    // ===== Phase 1: MFMA GEMM  C[4224 x 576] = Xb @ Bb^T ====================
    //   cols 0..511 -> VpH bf16 (+bv); 512..527 -> S fp32 ((acc+c0)*SCALE)
    // 64x64 tiles, 594 tiles (9 cols x 66 rows), block-stride.
    {
        ushort (*Xs)[72] = (ushort(*)[72])arena;              //  9216 B
        ushort (*Bs)[72] = (ushort(*)[72])(arena + 9216);     //  9216 B
        const int wave = tid >> 6, lane = tid & 63;
        const int wm = (wave >> 1) * 32, wn = (wave & 1) * 32;
        const int lr = lane & 15;
        const int quad = lane >> 4;

        for (int tile = blockIdx.x; tile < 9 * 66; tile += GRID) {
            const int rowBase = (tile / 9) * 64;
            const int colBase = (tile % 9) * 64;

            f32x4 acc[2][2];
            const f32x4 zero = {0.f, 0.f, 0.f, 0.f};
#pragma unroll
            for (int i = 0; i < 2; ++i) { acc[i][0] = zero; acc[i][1] = zero; }

            for (int k0 = 0; k0 < DD; k0 += 64) {
#pragma unroll
                for (int i = 0; i < 2; ++i) {
                    const int ch = tid + i * 256;
                    const int r = ch >> 3, cc = (ch & 7) * 8;
                    *(uint4*)&Xs[r][cc] = *(const uint4*)&Xb[(size_t)(rowBase + r) * DD + k0 + cc];
                    *(uint4*)&Bs[r][cc] = *(const uint4*)&Bb[(size_t)(colBase + r) * DD + k0 + cc];
                }
                __syncthreads();
#pragma unroll
                for (int kc = 0; kc < 2; ++kc) {
                    bf16x8 af[2], bfr[2];
#pragma unroll
                    for (int t = 0; t < 2; ++t)
                        af[t] = *(const bf16x8*)&Xs[wm + t * 16 + lr][kc * 32 + quad * 8];
#pragma unroll
                    for (int u = 0; u < 2; ++u)
                        bfr[u] = *(const bf16x8*)&Bs[wn + u * 16 + lr][kc * 32 + quad * 8];
#pragma unroll
                    for (int mt = 0; mt < 2; ++mt)
#pragma unroll
                        for (int nt = 0; nt < 2; ++nt)
                            acc[mt][nt] = __builtin_amdgcn_mfma_f32_16x16x32_bf16(
                                af[mt], bfr[nt], acc[mt][nt], 0, 0, 0);
                }
                __syncthreads();
            }

            // epilogue: C/D layout col = lane&15, row = quad*4 + r (m89/m91)
#pragma unroll
            for (int nt = 0; nt < 2; ++nt) {
                const int col = colBase + wn + nt * 16 + lr;
                const bool isV = (col < DD);
                const bool isS = (col >= DD) && (col < DD + QN);
                const float badd = isV ? bv[col] : (isS ? c0[col - DD] : 0.f);
#pragma unroll
                for (int mt = 0; mt < 2; ++mt) {
#pragma unroll
                    for (int r = 0; r < 4; ++r) {
                        const int row = rowBase + wm + mt * 16 + quad * 4 + r;
                        if (row < MEXT) {
                            const float v = acc[mt][nt][r];
                            if (isV)      VpH[(size_t)row * DD + col] = f2bf(v + badd);
                            else if (isS) S[row * QN + (col - DD)] = (v + badd) * SCALE;
                        }
                    }
                }
            }
        }
    }

    grid.sync();

    // ===== Phase 2: per-group aggregation (1 block per group) ===============
    {
        int*   idxs = (int*)arena;                       // 64
        int*   mval = idxs + PP;                         // 64
        int*   cidx = mval + PP;                         // 68
        int*   cp   = cidx + (PP + 4);                   // 68
        float (*scT)[QN] = (float(*)[QN])(cp + (PP + 4)); // [66][16], off 1056 (16B-aligned)
        float (*red)[4] = (float(*)[4])((float*)scT + 66 * QN);
        float* fwq  = (float*)red + QN * 4;
        int*   cntS = (int*)(fwq + QN);

        const int n = blockIdx.x;                        // GRID == NGRP
        // pos_mask storage-width detection (wave-uniform)
        const unsigned int* mw = (const unsigned int*)pmask;
        bool four = true;
#pragma unroll
        for (int i = 0; i < 16; ++i) {
            const unsigned int v = mw[i];
            four = four && (v == 0u || v == 1u || v == 0x3F800000u);
        }

        if (tid < PP) {
            idxs[tid] = indices[n * PP + tid];
            int mv;
            if (four) mv = (mw[n * PP + tid] != 0u);
            else      mv = (((const unsigned char*)pmask)[n * PP + tid] != 0);
            mval[tid] = mv;
            const bool a = (mv != 0);
            const unsigned long long m = __ballot(a);
            const int pos = __popcll(m & ((1ull << tid) - 1ull));
            if (a) { cidx[pos] = idxs[tid]; cp[pos] = tid; }
            if (tid == 0) *cntS = (int)__popcll(m);
        }
        __syncthreads();

        // gather scores (p-major), full 1024-entry fill
        for (int e = tid; e < QN * PP; e += 256) {
            const int p = e >> 4, q = e & 15;
            scT[p + 1][q] = mval[p] ? S[idxs[p] * QN + q] : -INFINITY;
        }
        if (tid < QN) scT[0][tid] = S[(NTOK + tid) * QN + tid];   // s_self[q]
        __syncthreads();

        if (tid < 4) { cidx[*cntS + tid] = 0; cp[*cntS + tid] = PP; }
        if (tid < QN) {                                  // softmax over 65 per q
            const int q = tid;
            float m = -INFINITY;
            for (int j = 0; j <= PP; ++j) m = fmaxf(m, scT[j][q]);
            float s = 0.f;
            for (int j = 0; j <= PP; ++j) { const float e = __expf(scT[j][q] - m); scT[j][q] = e; s += e; }
            const float inv = 1.f / s;
            for (int j = 0; j <= PP; ++j) scT[j][q] *= inv;
            scT[PP + 1][q] = 0.f;                        // pad weight = 0
        }
        __syncthreads();

        const int cnt4 = (*cntS + 3) & ~3;
        const int d0 = tid * 2;
        float pt[QN][2];
        {
            float2 vq[QN];
#pragma unroll
            for (int q = 0; q < QN; ++q)
                vq[q] = bfp2f2(*(const unsigned int*)&VpH[(size_t)(NTOK + q) * DD + d0]);
#pragma unroll
            for (int q = 0; q < QN; ++q) {
                const float w0 = scT[0][q];
                pt[q][0] = w0 * vq[q].x;
                pt[q][1] = w0 * vq[q].y;
            }
        }
        for (int j0 = 0; j0 < cnt4; j0 += 4) {
            float2 v[4]; int p[4];
#pragma unroll
            for (int pi = 0; pi < 4; ++pi) {
                v[pi] = bfp2f2(*(const unsigned int*)&VpH[(size_t)cidx[j0 + pi] * DD + d0]);
                p[pi] = cp[j0 + pi] + 1;
            }
#pragma unroll
            for (int pi = 0; pi < 4; ++pi) {
                const float4 wa = *(const float4*)&scT[p[pi]][0];
                const float4 wb = *(const float4*)&scT[p[pi]][4];
                const float4 wc = *(const float4*)&scT[p[pi]][8];
                const float4 wd = *(const float4*)&scT[p[pi]][12];
                const float vx = v[pi].x, vy = v[pi].y;
                pt[ 0][0] += wa.x*vx; pt[ 0][1] += wa.x*vy;
                pt[ 1][0] += wa.y*vx; pt[ 1][1] += wa.y*vy;
                pt[ 2][0] += wa.z*vx; pt[ 2][1] += wa.z*vy;
                pt[ 3][0] += wa.w*vx; pt[ 3][1] += wa.w*vy;
                pt[ 4][0] += wb.x*vx; pt[ 4][1] += wb.x*vy;
                pt[ 5][0] += wb.y*vx; pt[ 5][1] += wb.y*vy;
                pt[ 6][0] += wb.z*vx; pt[ 6][1] += wb.z*vy;
                pt[ 7][0] += wb.w*vx; pt[ 7][1] += wb.w*vy;
                pt[ 8][0] += wc.x*vx; pt[ 8][1] += wc.x*vy;
                pt[ 9][0] += wc.y*vx; pt[ 9][1] += wc.y*vy;
                pt[10][0] += wc.z*vx; pt[10][1] += wc.z*vy;
                pt[11][0] += wc.w*vx; pt[11][1] += wc.w*vy;
                pt[12][0] += wd.x*vx; pt[12][1] += wd.x*vy;
                pt[13][0] += wd.y*vx; pt[13][1] += wd.y*vy;
                pt[14][0] += wd.z*vx; pt[14][1] += wd.z*vy;
                pt[15][0] += wd.w*vx; pt[15][1] += wd.w*vy;
            }
        }

        // fusion logits f[q] = pt[q,:] . Wf + bf
        const float wf0 = Wf[d0], wf1 = Wf[d0 + 1];
        const int wid = tid >> 6, lane = tid & 63;
#pragma unroll
        for (int q = 0; q < QN; ++q) {
            float s = pt[q][0] * wf0 + pt[q][1] * wf1;
#pragma unroll
            for (int off = 32; off > 0; off >>= 1) s += __shfl_down(s, off, 64);
            if (lane == 0) red[q][wid] = s;
        }
        __syncthreads();
        if (tid == 0) {
            float f[QN];
            float m = -INFINITY;
#pragma unroll
            for (int q = 0; q < QN; ++q) {
                f[q] = red[q][0] + red[q][1] + red[q][2] + red[q][3] + bf[0];
                m = fmaxf(m, f[q]);
            }
            float ssum = 0.f;
#pragma unroll
            for (int q = 0; q < QN; ++q) { f[q] = __expf(f[q] - m); ssum += f[q]; }
            const float inv = 1.f / ssum;
#pragma unroll
            for (int q = 0; q < QN; ++q) fwq[q] = f[q] * inv;
        }
        __syncthreads();

        float o0 = 0.f, o1 = 0.f;
#pragma unroll
        for (int q = 0; q < QN; ++q) {
            const float w = fwq[q];
            o0 += pt[q][0] * w;
            o1 += pt[q][1] * w;
        }
        *(float2*)&out[(size_t)n * DD + d0] = make_float2(o0, o1);
    }
}

// ---------------------------------------------------------------------------
extern "C" void kernel_launch(void* const* d_in, const int* in_sizes, int n_in,
                              void* d_out, int out_size, void* d_ws, size_t ws_size,
                              hipStream_t stream)
{
    const float* patch   = (const float*)d_in[0];
    const float* query   = (const float*)d_in[1];
    const float* Wk      = (const float*)d_in[2];
    const float* bk      = (const float*)d_in[3];
    const float* Wv      = (const float*)d_in[4];
    const float* bv      = (const float*)d_in[5];
    const float* Wf      = (const float*)d_in[6];
    const float* bf      = (const float*)d_in[7];
    const int*   indices = (const int*)d_in[8];
    const void*  pmask   = d_in[9];
    float* out = (float*)d_out;

    // ws: VpH bf16[MEXT*DD] | S f32[MEXT*QN] | c0 f32[16]
    //     | Xb bf16[MPAD*DD] | Bb bf16[NB*DD]     (~9.4 MB of 256 MiB ws)
    ushort* VpH = (ushort*)d_ws;
    float*  S   = (float*)(VpH + (size_t)MEXT * DD);
    float*  c0  = S + (size_t)MEXT * QN;
    ushort* Xb  = (ushort*)(c0 + 16);
    ushort* Bb  = Xb + (size_t)MPAD * DD;

    void* args[] = {
        (void*)&patch, (void*)&query, (void*)&Wk, (void*)&bk,
        (void*)&Wv, (void*)&bv, (void*)&Wf, (void*)&bf,
        (void*)&indices, (void*)&pmask,
        (void*)&Xb, (void*)&Bb, (void*)&c0, (void*)&VpH, (void*)&S, (void*)&out
    };
    hipLaunchCooperativeKernel((const void*)fused, dim3(GRID), dim3(256),
                               args, 0, stream);
}

// Round 7
// 122.311 us; speedup vs baseline: 2.1311x; 2.1311x over previous
//
#include <hip/hip_runtime.h>
#include <hip/hip_bf16.h>
#include <math.h>

// Problem constants: B=32, L=128, D=512, Qn=16, N=512, P=64
#define DD    512
#define QN    16
#define NTOK  4096
#define MEXT  4112           // NTOK + QN
#define MPAD  4224           // 66 * 64
#define NGRP  512
#define PP    64
#define NB    576            // padded B rows: 512 Wv + 16 score + 48 pad (9 tiles)
#define SCALE 0.04419417382415922f   // 1/sqrt(512)

typedef __bf16 bf16x8 __attribute__((ext_vector_type(8)));
typedef float  f32x4  __attribute__((ext_vector_type(4)));

static __device__ __forceinline__ ushort f2bf(float f) {
    __hip_bfloat16 h = __float2bfloat16(f);
    return *reinterpret_cast<ushort*>(&h);
}
// unpack 2 packed bf16 (little-endian: low ushort = element 0) to fp32
static __device__ __forceinline__ float2 bfp2f2(unsigned int v) {
    float2 r;
    r.x = __uint_as_float(v << 16);
    r.y = __uint_as_float(v & 0xffff0000u);
    return r;
}

// ---------------------------------------------------------------------------
// pack_all: one kernel, block-range dispatch (no cross-range dependencies).
//  [0,1056)    : Xb = bf16([patch ; Q0 ; zeros])              (4224 x 512)
//  [1056,1120) : Bb rows 0..511   = bf16(Wv^T)  (64x64 LDS-tile transpose)
//  [1120,1132) : Bb rows 528..575 = 0
//  [1132,1264) : Bb rows 512..527 = bf16(Wk @ Q0^T), + c0[q] = bk.Q0[q]
// ---------------------------------------------------------------------------
__global__ __launch_bounds__(256) void pack_all(
    const float* __restrict__ patch, const float* __restrict__ query,
    const float* __restrict__ Wv, const float* __restrict__ Wk,
    const float* __restrict__ bk,
    ushort* __restrict__ Xb, ushort* __restrict__ Bb, float* __restrict__ c0)
{
    __shared__ float T[64][65];
    const int b = blockIdx.x;
    const int tid = threadIdx.x;
    if (b < 1056) {                       // X cast: 8 elems/thread
        const int e0 = b * 2048 + tid * 8;
        const int row = e0 >> 9, c = e0 & 511;
        float v[8];
        if (row < NTOK) {
            const float4 a0 = *(const float4*)&patch[(size_t)row * DD + c];
            const float4 a1 = *(const float4*)&patch[(size_t)row * DD + c + 4];
            v[0]=a0.x; v[1]=a0.y; v[2]=a0.z; v[3]=a0.w;
            v[4]=a1.x; v[5]=a1.y; v[6]=a1.z; v[7]=a1.w;
        } else if (row < MEXT) {
            const float4 a0 = *(const float4*)&query[(size_t)(row - NTOK) * DD + c];
            const float4 a1 = *(const float4*)&query[(size_t)(row - NTOK) * DD + c + 4];
            v[0]=a0.x; v[1]=a0.y; v[2]=a0.z; v[3]=a0.w;
            v[4]=a1.x; v[5]=a1.y; v[6]=a1.z; v[7]=a1.w;
        } else {
#pragma unroll
            for (int j = 0; j < 8; ++j) v[j] = 0.f;
        }
        ushort o[8];
#pragma unroll
        for (int j = 0; j < 8; ++j) o[j] = f2bf(v[j]);
        *(uint4*)&Xb[e0] = *(const uint4*)o;
    } else if (b < 1120) {                // Wv transpose, 64x64 tile
        const int t = b - 1056;
        const int k0 = (t >> 3) * 64, n0 = (t & 7) * 64;
#pragma unroll
        for (int j = 0; j < 16; ++j) {
            const int idx = tid + j * 256;
            const int r = idx >> 6, c = idx & 63;
            T[r][c] = Wv[(size_t)(k0 + r) * DD + n0 + c];
        }
        __syncthreads();
#pragma unroll
        for (int j = 0; j < 16; ++j) {
            const int idx = tid + j * 256;
            const int r = idx >> 6, c = idx & 63;
            Bb[(size_t)(n0 + r) * DD + k0 + c] = f2bf(T[c][r]);
        }
    } else if (b < 1132) {                // zero rows 528..575
        const int e0 = (b - 1120) * 2048 + tid * 8;
        *(uint4*)&Bb[(size_t)528 * DD + e0] = make_uint4(0, 0, 0, 0);
    } else {                              // A (score B-rows) + c0
        const int wave = tid >> 6, lane = tid & 63;
        const int g = (b - 1132) * 4 + wave;
        if (g < DD) {
            const int e = g;
            float x[8];
#pragma unroll
            for (int j = 0; j < 8; ++j) x[j] = Wk[e * DD + j * 64 + lane];
            for (int q = 0; q < QN; ++q) {
                float s = 0.f;
#pragma unroll
                for (int j = 0; j < 8; ++j) s += x[j] * query[q * DD + j * 64 + lane];
#pragma unroll
                for (int off = 32; off > 0; off >>= 1) s += __shfl_down(s, off, 64);
                if (lane == 0) Bb[(size_t)(DD + q) * DD + e] = f2bf(s);
            }
        } else {
            const int q = g - DD;
            float s = 0.f;
#pragma unroll
            for (int j = 0; j < 8; ++j)
                s += bk[j * 64 + lane] * query[q * DD + j * 64 + lane];
#pragma unroll
            for (int off = 32; off > 0; off >>= 1) s += __shfl_down(s, off, 64);
            if (lane == 0) c0[q] = s;
        }
    }
}

// ---------------------------------------------------------------------------
// K2: fused MFMA GEMM  C[4224 x 576] = Xb @ Bb^T  (Bb stored [n][k])
//   cols 0..511   -> VpH bf16 (+ bv);  cols 512..527 -> S fp32 ((acc+c0)*SCALE)
// 64x64 block tile, 256 thr (4 waves: 2x2, each 32x32 via 2x2 MFMA tiles),
// BK=64, bf16 16x16x32 MFMA. grid (9, 66) = 594 blocks.
// ---------------------------------------------------------------------------
__global__ __launch_bounds__(256) void k2_mfma(
    const ushort* __restrict__ Xb, const ushort* __restrict__ Bb,
    const float* __restrict__ bv, const float* __restrict__ c0,
    ushort* __restrict__ VpH, float* __restrict__ S)
{
    __shared__ __align__(16) ushort Xs[64][72];   // +8 pad (m97 pattern)
    __shared__ __align__(16) ushort Bs[64][72];
    const int tid = threadIdx.x;
    const int rowBase = blockIdx.y * 64;
    const int colBase = blockIdx.x * 64;
    const int wave = tid >> 6, lane = tid & 63;
    const int wm = (wave >> 1) * 32, wn = (wave & 1) * 32;
    const int lr = lane & 15;
    const int quad = lane >> 4;

    f32x4 acc[2][2];
    const f32x4 zero = {0.f, 0.f, 0.f, 0.f};
#pragma unroll
    for (int i = 0; i < 2; ++i) { acc[i][0] = zero; acc[i][1] = zero; }

    for (int k0 = 0; k0 < DD; k0 += 64) {
#pragma unroll
        for (int i = 0; i < 2; ++i) {          // X: 512 16B chunks
            const int ch = tid + i * 256;
            const int r = ch >> 3, cc = (ch & 7) * 8;
            *(uint4*)&Xs[r][cc] = *(const uint4*)&Xb[(size_t)(rowBase + r) * DD + k0 + cc];
            *(uint4*)&Bs[r][cc] = *(const uint4*)&Bb[(size_t)(colBase + r) * DD + k0 + cc];
        }
        __syncthreads();
#pragma unroll
        for (int kc = 0; kc < 2; ++kc) {
            bf16x8 af[2], bfr[2];
#pragma unroll
            for (int t = 0; t < 2; ++t)
                af[t] = *(const bf16x8*)&Xs[wm + t * 16 + lr][kc * 32 + quad * 8];
#pragma unroll
            for (int u = 0; u < 2; ++u)
                bfr[u] = *(const bf16x8*)&Bs[wn + u * 16 + lr][kc * 32 + quad * 8];
#pragma unroll
            for (int mt = 0; mt < 2; ++mt)
#pragma unroll
                for (int nt = 0; nt < 2; ++nt)
                    acc[mt][nt] = __builtin_amdgcn_mfma_f32_16x16x32_bf16(
                        af[mt], bfr[nt], acc[mt][nt], 0, 0, 0);
        }
        __syncthreads();
    }

    // epilogue: C/D layout col = lane&15, row = quad*4 + r (m89/m91)
#pragma unroll
    for (int nt = 0; nt < 2; ++nt) {
        const int col = colBase + wn + nt * 16 + lr;
        const bool isV = (col < DD);
        const bool isS = (col >= DD) && (col < DD + QN);
        const float badd = isV ? bv[col] : (isS ? c0[col - DD] : 0.f);
#pragma unroll
        for (int mt = 0; mt < 2; ++mt) {
#pragma unroll
            for (int r = 0; r < 4; ++r) {
                const int row = rowBase + wm + mt * 16 + quad * 4 + r;
                if (row < MEXT) {
                    const float v = acc[mt][nt][r];
                    if (isV)      VpH[(size_t)row * DD + col] = f2bf(v + badd);
                    else if (isS) S[row * QN + (col - DD)] = (v + badd) * SCALE;
                }
            }
        }
    }
}

// ---------------------------------------------------------------------------
// K4: per-group aggregation. Vp gathered as bf16 (4.2 MB, L2/L3-resident).
// Weights p-major in LDS (scT[p][q]) -> broadcast float4 reads, conflict-free.
// ---------------------------------------------------------------------------
__global__ __launch_bounds__(256) void k4_agg(
    const ushort* __restrict__ VpH,    // MEXT x D bf16 (rows >= NTOK are VQ)
    const float* __restrict__ S,       // MEXT x QN
    const int* __restrict__ indices,
    const void* __restrict__ pmask,
    const float* __restrict__ Wf, const float* __restrict__ bf,
    float* __restrict__ out)
{
    __shared__ int   idxs[PP];
    __shared__ int   mval[PP];
    __shared__ int   cidx[PP + 4];
    __shared__ int   cp[PP + 4];
    __shared__ float scT[PP + 2][QN];  // row0=self, 1..64=gathered, 65=zero pad
    __shared__ float red[QN][4];
    __shared__ float fwq[QN];
    __shared__ int   cntS;

    const int n = blockIdx.x;
    const int tid = threadIdx.x;

    // pos_mask storage-width detection (wave-uniform)
    const unsigned int* mw = (const unsigned int*)pmask;
    bool four = true;
#pragma unroll
    for (int i = 0; i < 16; ++i) {
        const unsigned int v = mw[i];
        four = four && (v == 0u || v == 1u || v == 0x3F800000u);
    }

    if (tid < PP) {
        idxs[tid] = indices[n * PP + tid];
        int mv;
        if (four) mv = (mw[n * PP + tid] != 0u);
        else      mv = (((const unsigned char*)pmask)[n * PP + tid] != 0);
        mval[tid] = mv;
        const bool a = (mv != 0);
        const unsigned long long m = __ballot(a);
        const int pos = __popcll(m & ((1ull << tid) - 1ull));
        if (a) { cidx[pos] = idxs[tid]; cp[pos] = tid; }
        if (tid == 0) cntS = (int)__popcll(m);
    }
    __syncthreads();

    // gather scores (p-major), full 1024-entry fill
    for (int e = tid; e < QN * PP; e += 256) {
        const int p = e >> 4, q = e & 15;
        scT[p + 1][q] = mval[p] ? S[idxs[p] * QN + q] : -INFINITY;
    }
    if (tid < QN) scT[0][tid] = S[(NTOK + tid) * QN + tid];   // s_self[q]
    __syncthreads();

    if (tid < 4) { cidx[cntS + tid] = 0; cp[cntS + tid] = PP; }  // pad entries
    if (tid < QN) {                                  // softmax over 65 per q
        const int q = tid;
        float m = -INFINITY;
        for (int j = 0; j <= PP; ++j) m = fmaxf(m, scT[j][q]);
        float s = 0.f;
        for (int j = 0; j <= PP; ++j) { const float e = __expf(scT[j][q] - m); scT[j][q] = e; s += e; }
        const float inv = 1.f / s;
        for (int j = 0; j <= PP; ++j) scT[j][q] *= inv;
        scT[PP + 1][q] = 0.f;                        // pad weight = 0
    }
    __syncthreads();

    const int cnt4 = (cntS + 3) & ~3;
    const int d0 = tid * 2;
    float pt[QN][2];
    {
        float2 vq[QN];
#pragma unroll
        for (int q = 0; q < QN; ++q)
            vq[q] = bfp2f2(*(const unsigned int*)&VpH[(size_t)(NTOK + q) * DD + d0]);
#pragma unroll
        for (int q = 0; q < QN; ++q) {
            const float w0 = scT[0][q];
            pt[q][0] = w0 * vq[q].x;
            pt[q][1] = w0 * vq[q].y;
        }
    }
    for (int j0 = 0; j0 < cnt4; j0 += 4) {
        float2 v[4]; int p[4];
#pragma unroll
        for (int pi = 0; pi < 4; ++pi) {
            v[pi] = bfp2f2(*(const unsigned int*)&VpH[(size_t)cidx[j0 + pi] * DD + d0]);
            p[pi] = cp[j0 + pi] + 1;
        }
#pragma unroll
        for (int pi = 0; pi < 4; ++pi) {
            const float4 wa = *(const float4*)&scT[p[pi]][0];
            const float4 wb = *(const float4*)&scT[p[pi]][4];
            const float4 wc = *(const float4*)&scT[p[pi]][8];
            const float4 wd = *(const float4*)&scT[p[pi]][12];
            const float vx = v[pi].x, vy = v[pi].y;
            pt[ 0][0] += wa.x*vx; pt[ 0][1] += wa.x*vy;
            pt[ 1][0] += wa.y*vx; pt[ 1][1] += wa.y*vy;
            pt[ 2][0] += wa.z*vx; pt[ 2][1] += wa.z*vy;
            pt[ 3][0] += wa.w*vx; pt[ 3][1] += wa.w*vy;
            pt[ 4][0] += wb.x*vx; pt[ 4][1] += wb.x*vy;
            pt[ 5][0] += wb.y*vx; pt[ 5][1] += wb.y*vy;
            pt[ 6][0] += wb.z*vx; pt[ 6][1] += wb.z*vy;
            pt[ 7][0] += wb.w*vx; pt[ 7][1] += wb.w*vy;
            pt[ 8][0] += wc.x*vx; pt[ 8][1] += wc.x*vy;
            pt[ 9][0] += wc.y*vx; pt[ 9][1] += wc.y*vy;
            pt[10][0] += wc.z*vx; pt[10][1] += wc.z*vy;
            pt[11][0] += wc.w*vx; pt[11][1] += wc.w*vy;
            pt[12][0] += wd.x*vx; pt[12][1] += wd.x*vy;
            pt[13][0] += wd.y*vx; pt[13][1] += wd.y*vy;
            pt[14][0] += wd.z*vx; pt[14][1] += wd.z*vy;
            pt[15][0] += wd.w*vx; pt[15][1] += wd.w*vy;
        }
    }

    // fusion logits f[q] = pt[q,:] . Wf + bf
    const float wf0 = Wf[d0], wf1 = Wf[d0 + 1];
    const int wid = tid >> 6, lane = tid & 63;
#pragma unroll
    for (int q = 0; q < QN; ++q) {
        float s = pt[q][0] * wf0 + pt[q][1] * wf1;
#pragma unroll
        for (int off = 32; off > 0; off >>= 1) s += __shfl_down(s, off, 64);
        if (lane == 0) red[q][wid] = s;
    }
    __syncthreads();
    if (tid == 0) {
        float f[QN];
        float m = -INFINITY;
#pragma unroll
        for (int q = 0; q < QN; ++q) {
            f[q] = red[q][0] + red[q][1] + red[q][2] + red[q][3] + bf[0];
            m = fmaxf(m, f[q]);
        }
        float ssum = 0.f;
#pragma unroll
        for (int q = 0; q < QN; ++q) { f[q] = __expf(f[q] - m); ssum += f[q]; }
        const float inv = 1.f / ssum;
#pragma unroll
        for (int q = 0; q < QN; ++q) fwq[q] = f[q] * inv;
    }
    __syncthreads();

    float o0 = 0.f, o1 = 0.f;
#pragma unroll
    for (int q = 0; q < QN; ++q) {
        const float w = fwq[q];
        o0 += pt[q][0] * w;
        o1 += pt[q][1] * w;
    }
    *(float2*)&out[(size_t)n * DD + d0] = make_float2(o0, o1);
}

// ---------------------------------------------------------------------------
extern "C" void kernel_launch(void* const* d_in, const int* in_sizes, int n_in,
                              void* d_out, int out_size, void* d_ws, size_t ws_size,
                              hipStream_t stream)
{
    const float* patch   = (const float*)d_in[0];
    const float* query   = (const float*)d_in[1];
    const float* Wk      = (const float*)d_in[2];
    const float* bk      = (const float*)d_in[3];
    const float* Wv      = (const float*)d_in[4];
    const float* bv      = (const float*)d_in[5];
    const float* Wf      = (const float*)d_in[6];
    const float* bf      = (const float*)d_in[7];
    const int*   indices = (const int*)d_in[8];
    const void*  pmask   = d_in[9];
    float* out = (float*)d_out;

    // ws: VpH bf16[MEXT*DD] | S f32[MEXT*QN] | c0 f32[16]
    //     | Xb bf16[MPAD*DD] | Bb bf16[NB*DD]     (~9.4 MB of 256 MiB ws)
    ushort* VpH = (ushort*)d_ws;
    float*  S   = (float*)(VpH + (size_t)MEXT * DD);
    float*  c0  = S + (size_t)MEXT * QN;
    ushort* Xb  = (ushort*)(c0 + 16);
    ushort* Bb  = Xb + (size_t)MPAD * DD;

    pack_all<<<dim3(1264), dim3(256), 0, stream>>>(patch, query, Wv, Wk, bk, Xb, Bb, c0);
    k2_mfma <<<dim3(9, 66), dim3(256), 0, stream>>>(Xb, Bb, bv, c0, VpH, S);
    k4_agg  <<<dim3(NGRP), dim3(256), 0, stream>>>(VpH, S, indices, pmask, Wf, bf, out);
}